// Round 7
// baseline (406.304 us; speedup 1.0000x reference)
//
#include <hip/hip_runtime.h>

// Problem constants (match reference setup_inputs)
constexpr int NV = 100000;   // vertices
constexpr int NE = 1600000;  // directed edges
constexpr int NB = 64;       // graphs
constexpr int HD = 128;      // hidden
constexpr int DM = 256;      // out dim
#define EPSLN 1e-5f

// CSR bucketing
constexpr int DPB   = 512;                      // dsts per bucket
constexpr int NBUCK = (NV + DPB - 1) / DPB;     // 196
constexpr int EPB   = 4096;                     // edges per block (bucket kernels)
constexpr int NEB   = (NE + EPB - 1) / EPB;     // 391

typedef short bf16x8 __attribute__((ext_vector_type(8)));
typedef float f32x4 __attribute__((ext_vector_type(4)));

__device__ inline unsigned short f2b(float f) {
    union { float f; unsigned u; } x; x.f = f;
    unsigned r = x.u + 0x7FFF + ((x.u >> 16) & 1);
    return (unsigned short)(r >> 16);
}
__device__ inline float b2f(unsigned short h) {
    union { unsigned u; float f; } x; x.u = (unsigned)h << 16;
    return x.f;
}

// ---------- bucket histogram: count edges per dst-bucket ----------
__global__ __launch_bounds__(256) void k_bhist(const int* __restrict__ ei,
                                               int* __restrict__ bcount) {
    __shared__ int h[NBUCK];
    int t = threadIdx.x;
    for (int i = t; i < NBUCK; i += 256) h[i] = 0;
    __syncthreads();
    int base = blockIdx.x * EPB;
    #pragma unroll
    for (int j = 0; j < EPB / 256; ++j) {
        int idx = base + j * 256 + t;
        if (idx < NE) atomicAdd(&h[ei[NE + idx] >> 9], 1);
    }
    __syncthreads();
    for (int i = t; i < NBUCK; i += 256) if (h[i]) atomicAdd(&bcount[i], h[i]);
}

__global__ void k_bscan(const int* __restrict__ bcount, int* __restrict__ bstart,
                        int* __restrict__ bcursor) {
    if (threadIdx.x == 0 && blockIdx.x == 0) {
        int run = 0;
        for (int i = 0; i < NBUCK; ++i) { bstart[i] = run; bcursor[i] = run; run += bcount[i]; }
        bstart[NBUCK] = run;
    }
}

// ---------- scatter edges into bucket regions (packed: (src<<9)|dstloc) ----------
__global__ __launch_bounds__(256) void k_bscatter(const int* __restrict__ ei,
                                                  int* __restrict__ bcursor,
                                                  int* __restrict__ ebuf) {
    __shared__ int h[NBUCK];
    __shared__ int lbase[NBUCK];
    int t = threadIdx.x;
    for (int i = t; i < NBUCK; i += 256) h[i] = 0;
    __syncthreads();
    int base = blockIdx.x * EPB;
    int s[16], d[16], rk[16];
    #pragma unroll
    for (int j = 0; j < 16; ++j) {
        int idx = base + j * 256 + t;
        if (idx < NE) {
            s[j] = ei[idx];
            d[j] = ei[NE + idx];
            rk[j] = atomicAdd(&h[d[j] >> 9], 1);
        } else d[j] = -1;
    }
    __syncthreads();
    for (int i = t; i < NBUCK; i += 256) {
        int c = h[i];
        if (c) lbase[i] = atomicAdd(&bcursor[i], c);
    }
    __syncthreads();
    #pragma unroll
    for (int j = 0; j < 16; ++j)
        if (d[j] >= 0) ebuf[lbase[d[j] >> 9] + rk[j]] = (s[j] << 9) | (d[j] & 511);
}

// ---------- per-bucket: histogram -> local scan -> deg/dinv/rowstart ----------
__global__ __launch_bounds__(256) void k_bcsr_a(const int* __restrict__ ebuf,
                                                const int* __restrict__ bstart,
                                                int* __restrict__ degi,
                                                float* __restrict__ dinv,
                                                int* __restrict__ rowstart) {
    __shared__ int h[DPB];
    __shared__ int sdata[256];
    int b = blockIdx.x, t = threadIdx.x, d0 = b * DPB;
    for (int i = t; i < DPB; i += 256) h[i] = 0;
    __syncthreads();
    int e0 = bstart[b], e1 = bstart[b + 1];
    for (int e = e0 + t; e < e1; e += 256) atomicAdd(&h[ebuf[e] & 511], 1);
    __syncthreads();
    int a = h[2 * t], c = h[2 * t + 1];
    sdata[t] = a + c;
    __syncthreads();
    for (int off = 1; off < 256; off <<= 1) {
        int v = sdata[t];
        int add = (t >= off) ? sdata[t - off] : 0;
        __syncthreads();
        sdata[t] = v + add;
        __syncthreads();
    }
    int excl = (t == 0) ? 0 : sdata[t - 1];
    int base = bstart[b];
    int v0 = d0 + 2 * t, v1 = v0 + 1;
    if (v0 < NV) { rowstart[v0] = base + excl;     degi[v0] = a; dinv[v0] = rsqrtf((float)a + 1.0f); }
    if (v1 < NV) { rowstart[v1] = base + excl + a; degi[v1] = c; dinv[v1] = rsqrtf((float)c + 1.0f); }
}

// ---------- per-bucket CSR fill with precomputed edge weights ----------
__global__ __launch_bounds__(256) void k_bcsr_b(const int* __restrict__ ebuf,
                                                const int* __restrict__ bstart,
                                                const int* __restrict__ rowstart,
                                                const float* __restrict__ dinv,
                                                int2* __restrict__ csw) {
    __shared__ int cur[DPB];
    __shared__ float dlv[DPB];
    int b = blockIdx.x, t = threadIdx.x, d0 = b * DPB;
    for (int i = t; i < DPB; i += 256) {
        int v = d0 + i;
        cur[i] = (v < NV) ? rowstart[v] : 0;
        dlv[i] = (v < NV) ? dinv[v] : 0.f;
    }
    __syncthreads();
    int e0 = bstart[b], e1 = bstart[b + 1];
    for (int e = e0 + t; e < e1; e += 256) {
        int p = ebuf[e];
        int s = p >> 9;
        int dl = p & 511;
        int slot = atomicAdd(&cur[dl], 1);
        float w = dinv[s] * dlv[dl];
        csw[slot] = make_int2(s, __float_as_int(w));
    }
}

// ---------- fold layer-1: Wc = Win @ W1 (3x128), bc = bin @ W1 (128) ----------
__global__ void k_wc(const float* __restrict__ Win, const float* __restrict__ bin,
                     const float* __restrict__ W1, float* __restrict__ Wc,
                     float* __restrict__ bc) {
    int c = threadIdx.x;
    float w0 = 0.f, w1 = 0.f, w2 = 0.f, bv = 0.f;
    for (int k = 0; k < HD; ++k) {
        float w = W1[k * HD + c];
        w0 = fmaf(Win[k], w, w0);
        w1 = fmaf(Win[128 + k], w, w1);
        w2 = fmaf(Win[256 + k], w, w2);
        bv = fmaf(bin[k], w, bv);
    }
    Wc[c] = w0; Wc[128 + c] = w1; Wc[256 + c] = w2; bc[c] = bv;
}

// ---------- layer-1 H directly from vertices (f32 throughout) ----------
__global__ void k_h1(const float* __restrict__ verts, const float* __restrict__ Wc,
                     const float* __restrict__ bc, unsigned short* __restrict__ Hb) {
    int idx = blockIdx.x * 256 + threadIdx.x;
    if (idx >= NV * HD) return;
    int v = idx >> 7, c = idx & 127;
    float a = verts[v * 3 + 0], b = verts[v * 3 + 1], d = verts[v * 3 + 2];
    Hb[idx] = f2b(bc[c] + a * Wc[c] + b * Wc[128 + c] + d * Wc[256 + c]);
}

// ---------- W2,W3 [k][n] f32 -> Wt [l][n][k] bf16 ----------
__global__ void k_wt2(const float* __restrict__ W2, const float* __restrict__ W3,
                      unsigned short* __restrict__ Wt) {
    int idx = blockIdx.x * 256 + threadIdx.x;
    if (idx >= 2 * HD * HD) return;
    int l = idx >> 14, r = idx & 16383;
    const float* W = (l == 0) ? W2 : W3;
    int n = r >> 7, k = r & 127;
    Wt[idx - r + n * HD + k] = f2b(W[k * HD + n]);
}

// ---------- H = X @ W  via MFMA bf16: 4 waves/block, 64 rows/block ----------
__global__ __launch_bounds__(256) void k_gemm_mfma(const unsigned short* __restrict__ Xb,
                                                   const unsigned short* __restrict__ Wt,
                                                   unsigned short* __restrict__ Hb) {
    int wave = threadIdx.x >> 6;
    int lane = threadIdx.x & 63;
    int r = lane & 15;
    int g = lane >> 4;                     // 0..3
    int row0 = blockIdx.x * 64 + wave * 16;
    int arow = row0 + r;
    bool valid = arow < NV;

    bf16x8 afrag[4];
    const unsigned short* xp = Xb + (size_t)arow * HD + g * 8;
    #pragma unroll
    for (int ks = 0; ks < 4; ++ks) {
        if (valid) afrag[ks] = *(const bf16x8*)(xp + ks * 32);
        else       afrag[ks] = bf16x8{0, 0, 0, 0, 0, 0, 0, 0};
    }

    #pragma unroll
    for (int nt = 0; nt < 8; ++nt) {
        f32x4 acc = {0.f, 0.f, 0.f, 0.f};
        const unsigned short* wp = Wt + (size_t)(nt * 16 + r) * HD + g * 8;
        #pragma unroll
        for (int ks = 0; ks < 4; ++ks) {
            bf16x8 bfrag = *(const bf16x8*)(wp + ks * 32);
            acc = __builtin_amdgcn_mfma_f32_16x16x32_bf16(afrag[ks], bfrag, acc, 0, 0, 0);
        }
        #pragma unroll
        for (int j = 0; j < 4; ++j) {
            int row = row0 + g * 4 + j;   // C/D: col = lane&15, row = (lane>>4)*4 + reg
            if (row < NV)
                Hb[(size_t)row * HD + nt * 16 + r] = f2b(acc[j]);
        }
    }
}

// ---------- aggregate: one wave per dst, quarter-waves, precomputed weights ----------
__global__ __launch_bounds__(256) void k_agg(const unsigned short* __restrict__ H,
                                             const float* __restrict__ dinv,
                                             const int* __restrict__ rowstart,
                                             const int* __restrict__ degi,
                                             const int2* __restrict__ csw,
                                             const float* __restrict__ bias,
                                             unsigned short* __restrict__ Xo) {
    int gtid = blockIdx.x * 256 + threadIdx.x;
    int v = gtid >> 6;
    if (v >= NV) return;
    int lane = threadIdx.x & 63;
    int q = lane >> 4;        // quarter 0..3: edges q, q+4, q+8, ...
    int l4 = lane & 15;       // col group: cols l4*8 .. l4*8+7
    int rs = rowstart[v], len = degi[v];
    float a[8];
    if (q == 0) {
        float di = dinv[v];
        float sc = di * di;
        bf16x8 hv = *(const bf16x8*)(H + (size_t)v * HD + l4 * 8);
        #pragma unroll
        for (int jj = 0; jj < 8; ++jj) a[jj] = b2f((unsigned short)hv[jj]) * sc;
    } else {
        #pragma unroll
        for (int jj = 0; jj < 8; ++jj) a[jj] = 0.f;
    }
    int cnt = (len - q + 3) >> 2;   // edges this quarter handles
    int idx = rs + q;
    int j = 0;
    for (; j + 3 < cnt; j += 4) {
        int2 e0 = csw[idx], e1 = csw[idx + 4], e2 = csw[idx + 8], e3 = csw[idx + 12];
        idx += 16;
        bf16x8 h0 = *(const bf16x8*)(H + (size_t)e0.x * HD + l4 * 8);
        bf16x8 h1 = *(const bf16x8*)(H + (size_t)e1.x * HD + l4 * 8);
        bf16x8 h2 = *(const bf16x8*)(H + (size_t)e2.x * HD + l4 * 8);
        bf16x8 h3 = *(const bf16x8*)(H + (size_t)e3.x * HD + l4 * 8);
        float w0 = __int_as_float(e0.y), w1 = __int_as_float(e1.y);
        float w2 = __int_as_float(e2.y), w3 = __int_as_float(e3.y);
        #pragma unroll
        for (int jj = 0; jj < 8; ++jj) {
            a[jj] = fmaf(b2f((unsigned short)h0[jj]), w0, a[jj]);
            a[jj] = fmaf(b2f((unsigned short)h1[jj]), w1, a[jj]);
            a[jj] = fmaf(b2f((unsigned short)h2[jj]), w2, a[jj]);
            a[jj] = fmaf(b2f((unsigned short)h3[jj]), w3, a[jj]);
        }
    }
    for (; j < cnt; ++j) {
        int2 e0 = csw[idx];
        idx += 4;
        float w0 = __int_as_float(e0.y);
        bf16x8 h0 = *(const bf16x8*)(H + (size_t)e0.x * HD + l4 * 8);
        #pragma unroll
        for (int jj = 0; jj < 8; ++jj)
            a[jj] = fmaf(b2f((unsigned short)h0[jj]), w0, a[jj]);
    }
    // reduce across quarters (lanes l4, l4+16, l4+32, l4+48)
    #pragma unroll
    for (int jj = 0; jj < 8; ++jj) {
        a[jj] += __shfl_xor(a[jj], 16);
        a[jj] += __shfl_xor(a[jj], 32);
    }
    if (q == 0) {
        bf16x8 ov;
        #pragma unroll
        for (int jj = 0; jj < 8; ++jj)
            ov[jj] = (short)f2b(fmaxf(a[jj] + bias[l4 * 8 + jj], 0.f));
        *(bf16x8*)(Xo + (size_t)v * HD + l4 * 8) = ov;
    }
}

// ---------- mean pool: 2048 blocks x 256 thr, register run-length accumulate ----------
__global__ __launch_bounds__(256) void k_pool(const unsigned short* __restrict__ X,
                                              const int* __restrict__ batch,
                                              float* __restrict__ pool,
                                              int* __restrict__ cnt) {
    constexpr int NCHUNK = 2048;
    constexpr int CHUNK = (NV + NCHUNK - 1) / NCHUNK;  // 49
    int c = threadIdx.x & 127;   // column
    int r = threadIdx.x >> 7;    // 0..1 vertex-row offset
    int v0 = blockIdx.x * CHUNK;
    if (v0 >= NV) return;
    int vend = min(v0 + CHUNK, NV);
    int cur = -1;
    float sum = 0.f;
    for (int v = v0 + r; v < vend; v += 2) {
        int bb = batch[v];
        if (bb != cur) {
            if (cur >= 0) atomicAdd(&pool[cur * HD + c], sum);
            cur = bb; sum = 0.f;
        }
        sum += b2f(X[(size_t)v * HD + c]);
    }
    if (cur >= 0) atomicAdd(&pool[cur * HD + c], sum);
    if (threadIdx.x == 0) {
        int prev = batch[v0]; int c0 = 0;
        for (int v = v0; v < vend; ++v) {
            int bb = batch[v];
            if (bb != prev) { atomicAdd(&cnt[prev], c0); prev = bb; c0 = 0; }
            ++c0;
        }
        atomicAdd(&cnt[prev], c0);
    }
}

// ---------- final linear + layernorm, one block per graph ----------
__global__ __launch_bounds__(256) void k_out(const float* __restrict__ pool,
                                             const int* __restrict__ cnt,
                                             const float* __restrict__ Wout,
                                             const float* __restrict__ bout,
                                             const float* __restrict__ gamma,
                                             const float* __restrict__ beta,
                                             float* __restrict__ out) {
    __shared__ float ps[HD];
    __shared__ float red[DM];
    int g = blockIdx.x, t = threadIdx.x;
    if (t < HD) {
        float cn = fmaxf((float)cnt[g], 1.0f);
        ps[t] = pool[g * HD + t] / cn;
    }
    __syncthreads();
    float acc = bout[t];
    #pragma unroll 8
    for (int k = 0; k < HD; ++k) acc = fmaf(ps[k], Wout[k * DM + t], acc);
    red[t] = acc; __syncthreads();
    for (int s2 = 128; s2 > 0; s2 >>= 1) {
        if (t < s2) red[t] += red[t + s2];
        __syncthreads();
    }
    float mu = red[0] * (1.0f / DM);
    __syncthreads();
    float d = acc - mu;
    red[t] = d * d; __syncthreads();
    for (int s2 = 128; s2 > 0; s2 >>= 1) {
        if (t < s2) red[t] += red[t + s2];
        __syncthreads();
    }
    float var = red[0] * (1.0f / DM);
    out[g * DM + t] = d * rsqrtf(var + EPSLN) * gamma[t] + beta[t];
}

extern "C" void kernel_launch(void* const* d_in, const int* in_sizes, int n_in,
                              void* d_out, int out_size, void* d_ws, size_t ws_size,
                              hipStream_t stream) {
    const float* verts = (const float*)d_in[0];
    const int*   ei    = (const int*)d_in[1];
    const int*   batch = (const int*)d_in[2];
    const float* Win   = (const float*)d_in[3];
    const float* bin   = (const float*)d_in[4];
    const float* W1    = (const float*)d_in[5];
    const float* b1    = (const float*)d_in[6];
    const float* W2    = (const float*)d_in[7];
    const float* b2    = (const float*)d_in[8];
    const float* W3    = (const float*)d_in[9];
    const float* b3    = (const float*)d_in[10];
    const float* Wout  = (const float*)d_in[11];
    const float* bout  = (const float*)d_in[12];
    const float* gamma = (const float*)d_in[13];
    const float* beta  = (const float*)d_in[14];
    float* out = (float*)d_out;

    char* wp = (char*)d_ws;
    auto alloc = [&](size_t bytes) -> char* {
        char* p = wp;
        wp += (bytes + 255) & ~(size_t)255;
        return p;
    };
    unsigned short* Xb  = (unsigned short*)alloc((size_t)NV * HD * 2);
    unsigned short* Hb  = (unsigned short*)alloc((size_t)NV * HD * 2);
    unsigned short* Wt  = (unsigned short*)alloc((size_t)2 * HD * HD * 2);
    float* Wc       = (float*)alloc((size_t)3 * HD * 4);
    float* bc       = (float*)alloc((size_t)HD * 4);
    int*   degi     = (int*)alloc((size_t)NV * 4);
    float* dinv     = (float*)alloc((size_t)NV * 4);
    int*   rowstart = (int*)alloc((size_t)NV * 4);
    int2*  csw      = (int2*)alloc((size_t)NE * 8);
    int*   ebuf     = (int*)alloc((size_t)NE * 4);
    int*   bcount   = (int*)alloc((size_t)NBUCK * 4);
    int*   bstart   = (int*)alloc((size_t)(NBUCK + 1) * 4);
    int*   bcursor  = (int*)alloc((size_t)NBUCK * 4);
    float* pool     = (float*)alloc((size_t)NB * HD * 4);
    int*   cnt      = (int*)alloc((size_t)NB * 4);

    hipMemsetAsync(bcount, 0, (size_t)NBUCK * 4, stream);
    hipMemsetAsync(pool,   0, (size_t)NB * HD * 4, stream);
    hipMemsetAsync(cnt,    0, (size_t)NB * 4, stream);

    // CSR build (bucketed, L2-local, precomputed edge weights)
    k_bhist<<<NEB, 256, 0, stream>>>(ei, bcount);
    k_bscan<<<1, 64, 0, stream>>>(bcount, bstart, bcursor);
    k_bscatter<<<NEB, 256, 0, stream>>>(ei, bcursor, ebuf);
    k_bcsr_a<<<NBUCK, 256, 0, stream>>>(ebuf, bstart, degi, dinv, rowstart);
    k_bcsr_b<<<NBUCK, 256, 0, stream>>>(ebuf, bstart, rowstart, dinv, csw);

    // weights prep + layer-1 H (GEMM folded into 3-wide affine)
    k_wc<<<1, 128, 0, stream>>>(Win, bin, W1, Wc, bc);
    k_wt2<<<(2 * HD * HD + 255) / 256, 256, 0, stream>>>(W2, W3, Wt);
    k_h1<<<((size_t)NV * HD + 255) / 256, 256, 0, stream>>>(verts, Wc, bc, Hb);

    // layer 1 aggregate
    k_agg<<<((size_t)NV * 64 + 255) / 256, 256, 0, stream>>>(Hb, dinv, rowstart, degi, csw, b1, Xb);
    // layers 2,3
    const float* bl[2] = {b2, b3};
    for (int l = 0; l < 2; ++l) {
        k_gemm_mfma<<<(NV + 63) / 64, 256, 0, stream>>>(Xb, Wt + (size_t)l * HD * HD, Hb);
        k_agg<<<((size_t)NV * 64 + 255) / 256, 256, 0, stream>>>(Hb, dinv, rowstart, degi, csw, bl[l], Xb);
    }

    k_pool<<<2048, 256, 0, stream>>>(Xb, batch, pool, cnt);
    k_out<<<NB, 256, 0, stream>>>(pool, cnt, Wout, bout, gamma, beta, out);
}

// Round 8
// 370.249 us; speedup vs baseline: 1.0974x; 1.0974x over previous
//
#include <hip/hip_runtime.h>

// Problem constants (match reference setup_inputs)
constexpr int NV = 100000;   // vertices
constexpr int NE = 1600000;  // directed edges
constexpr int NB = 64;       // graphs
constexpr int HD = 128;      // hidden
constexpr int DM = 256;      // out dim
#define EPSLN 1e-5f

// CSR bucketing
constexpr int DPB   = 512;                      // dsts per bucket
constexpr int NBUCK = (NV + DPB - 1) / DPB;     // 196
constexpr int EPB   = 4096;                     // edges per block (bucket kernels)
constexpr int NEB   = (NE + EPB - 1) / EPB;     // 391

typedef short bf16x8 __attribute__((ext_vector_type(8)));
typedef float f32x4 __attribute__((ext_vector_type(4)));

__device__ inline unsigned short f2b(float f) {
    union { float f; unsigned u; } x; x.f = f;
    unsigned r = x.u + 0x7FFF + ((x.u >> 16) & 1);
    return (unsigned short)(r >> 16);
}
__device__ inline float b2f(unsigned short h) {
    union { unsigned u; float f; } x; x.u = (unsigned)h << 16;
    return x.f;
}

// ---------- bucket histogram: count edges per dst-bucket ----------
__global__ __launch_bounds__(256) void k_bhist(const int* __restrict__ ei,
                                               int* __restrict__ bcount) {
    __shared__ int h[NBUCK];
    int t = threadIdx.x;
    for (int i = t; i < NBUCK; i += 256) h[i] = 0;
    __syncthreads();
    int base = blockIdx.x * EPB;
    #pragma unroll
    for (int j = 0; j < EPB / 256; ++j) {
        int idx = base + j * 256 + t;
        if (idx < NE) atomicAdd(&h[ei[NE + idx] >> 9], 1);
    }
    __syncthreads();
    for (int i = t; i < NBUCK; i += 256) if (h[i]) atomicAdd(&bcount[i], h[i]);
}

__global__ void k_bscan(const int* __restrict__ bcount, int* __restrict__ bstart,
                        int* __restrict__ bcursor) {
    if (threadIdx.x == 0 && blockIdx.x == 0) {
        int run = 0;
        for (int i = 0; i < NBUCK; ++i) { bstart[i] = run; bcursor[i] = run; run += bcount[i]; }
        bstart[NBUCK] = run;
    }
}

// ---------- scatter edges into bucket regions (packed: (src<<9)|dstloc) ----------
__global__ __launch_bounds__(256) void k_bscatter(const int* __restrict__ ei,
                                                  int* __restrict__ bcursor,
                                                  int* __restrict__ ebuf) {
    __shared__ int h[NBUCK];
    __shared__ int lbase[NBUCK];
    int t = threadIdx.x;
    for (int i = t; i < NBUCK; i += 256) h[i] = 0;
    __syncthreads();
    int base = blockIdx.x * EPB;
    int s[16], d[16], rk[16];
    #pragma unroll
    for (int j = 0; j < 16; ++j) {
        int idx = base + j * 256 + t;
        if (idx < NE) {
            s[j] = ei[idx];
            d[j] = ei[NE + idx];
            rk[j] = atomicAdd(&h[d[j] >> 9], 1);
        } else d[j] = -1;
    }
    __syncthreads();
    for (int i = t; i < NBUCK; i += 256) {
        int c = h[i];
        if (c) lbase[i] = atomicAdd(&bcursor[i], c);
    }
    __syncthreads();
    #pragma unroll
    for (int j = 0; j < 16; ++j)
        if (d[j] >= 0) ebuf[lbase[d[j] >> 9] + rk[j]] = (s[j] << 9) | (d[j] & 511);
}

// ---------- fused per-bucket: histogram -> local scan -> deg/dinv/rowstart -> CSR fill ----------
__global__ __launch_bounds__(256) void k_bcsr(const int* __restrict__ ebuf,
                                              const int* __restrict__ bstart,
                                              int* __restrict__ degi,
                                              float* __restrict__ dinv,
                                              int* __restrict__ rowstart,
                                              int* __restrict__ csr) {
    __shared__ int h[DPB];
    __shared__ int sdata[256];
    int b = blockIdx.x, t = threadIdx.x, d0 = b * DPB;
    for (int i = t; i < DPB; i += 256) h[i] = 0;
    __syncthreads();
    int e0 = bstart[b], e1 = bstart[b + 1];
    for (int e = e0 + t; e < e1; e += 256) atomicAdd(&h[ebuf[e] & 511], 1);
    __syncthreads();
    int a = h[2 * t], c = h[2 * t + 1];
    sdata[t] = a + c;
    __syncthreads();
    for (int off = 1; off < 256; off <<= 1) {
        int v = sdata[t];
        int add = (t >= off) ? sdata[t - off] : 0;
        __syncthreads();
        sdata[t] = v + add;
        __syncthreads();
    }
    int excl = (t == 0) ? 0 : sdata[t - 1];
    int base = bstart[b];
    int v0 = d0 + 2 * t, v1 = v0 + 1;
    if (v0 < NV) { rowstart[v0] = base + excl;     degi[v0] = a; dinv[v0] = rsqrtf((float)a + 1.0f); }
    if (v1 < NV) { rowstart[v1] = base + excl + a; degi[v1] = c; dinv[v1] = rsqrtf((float)c + 1.0f); }
    // reuse h as cursors
    h[2 * t]     = base + excl;
    h[2 * t + 1] = base + excl + a;
    __syncthreads();
    for (int e = e0 + t; e < e1; e += 256) {
        int p = ebuf[e];
        int slot = atomicAdd(&h[p & 511], 1);
        csr[slot] = p >> 9;
    }
}

// ---------- layer-1 H from vertices; folds Wc = Win@W1, bc = bin@W1 per block ----------
__global__ __launch_bounds__(256) void k_h1(const float* __restrict__ verts,
                                            const float* __restrict__ Win,
                                            const float* __restrict__ bin,
                                            const float* __restrict__ W1,
                                            unsigned short* __restrict__ Hb) {
    __shared__ float Wc[3 * HD];
    __shared__ float bc[HD];
    int t = threadIdx.x;
    if (t < HD) {
        float w0 = 0.f, w1 = 0.f, w2 = 0.f, bv = 0.f;
        for (int k = 0; k < HD; ++k) {
            float w = W1[k * HD + t];
            w0 = fmaf(Win[k], w, w0);
            w1 = fmaf(Win[128 + k], w, w1);
            w2 = fmaf(Win[256 + k], w, w2);
            bv = fmaf(bin[k], w, bv);
        }
        Wc[t] = w0; Wc[128 + t] = w1; Wc[256 + t] = w2; bc[t] = bv;
    }
    __syncthreads();
    for (int idx = blockIdx.x * 256 + t; idx < NV * HD; idx += gridDim.x * 256) {
        int v = idx >> 7, c = idx & 127;
        float a = verts[v * 3 + 0], b = verts[v * 3 + 1], d = verts[v * 3 + 2];
        Hb[idx] = f2b(bc[c] + a * Wc[c] + b * Wc[128 + c] + d * Wc[256 + c]);
    }
}

// ---------- W2,W3 [k][n] f32 -> Wt [l][n][k] bf16 ----------
__global__ void k_wt2(const float* __restrict__ W2, const float* __restrict__ W3,
                      unsigned short* __restrict__ Wt) {
    int idx = blockIdx.x * 256 + threadIdx.x;
    if (idx >= 2 * HD * HD) return;
    int l = idx >> 14, r = idx & 16383;
    const float* W = (l == 0) ? W2 : W3;
    int n = r >> 7, k = r & 127;
    Wt[idx - r + n * HD + k] = f2b(W[k * HD + n]);
}

// ---------- FUSED aggregate + relu + GEMM(W_next): wave owns 16-dst tile ----------
__global__ __launch_bounds__(256) void k_aggf(const unsigned short* __restrict__ H,
                                              const float* __restrict__ dinv,
                                              const int* __restrict__ rowstart,
                                              const int* __restrict__ degi,
                                              const int* __restrict__ csr_src,
                                              const float* __restrict__ bias,
                                              const unsigned short* __restrict__ Wt,
                                              unsigned short* __restrict__ Hout) {
    __shared__ __align__(16) unsigned short xt[4][16][136];  // padded stride
    int wave = threadIdx.x >> 6;
    int lane = threadIdx.x & 63;
    int q = lane >> 4;        // quarter 0..3: edges q, q+4, ...
    int l4 = lane & 15;       // col group: cols l4*8 .. l4*8+7
    int v0 = blockIdx.x * 64 + wave * 16;
    if (v0 >= NV) return;

    // ---- aggregate 16 dst rows into LDS (relu'd bf16) ----
    for (int r = 0; r < 16; ++r) {
        int v = v0 + r;
        if (v >= NV) break;
        float di = dinv[v];
        int rs = rowstart[v], len = degi[v];
        float a[8];
        if (q == 0) {
            float sc = di * di;
            bf16x8 hv = *(const bf16x8*)(H + (size_t)v * HD + l4 * 8);
            #pragma unroll
            for (int jj = 0; jj < 8; ++jj) a[jj] = b2f((unsigned short)hv[jj]) * sc;
        } else {
            #pragma unroll
            for (int jj = 0; jj < 8; ++jj) a[jj] = 0.f;
        }
        int cnt = (len - q + 3) >> 2;
        int idx = rs + q;
        int j = 0;
        for (; j + 1 < cnt; j += 2) {
            int s0 = csr_src[idx], s1 = csr_src[idx + 4];
            idx += 8;
            float w0 = dinv[s0] * di, w1 = dinv[s1] * di;
            bf16x8 h0 = *(const bf16x8*)(H + (size_t)s0 * HD + l4 * 8);
            bf16x8 h1 = *(const bf16x8*)(H + (size_t)s1 * HD + l4 * 8);
            #pragma unroll
            for (int jj = 0; jj < 8; ++jj) {
                a[jj] = fmaf(b2f((unsigned short)h0[jj]), w0, a[jj]);
                a[jj] = fmaf(b2f((unsigned short)h1[jj]), w1, a[jj]);
            }
        }
        if (j < cnt) {
            int s0 = csr_src[idx];
            float w0 = dinv[s0] * di;
            bf16x8 h0 = *(const bf16x8*)(H + (size_t)s0 * HD + l4 * 8);
            #pragma unroll
            for (int jj = 0; jj < 8; ++jj)
                a[jj] = fmaf(b2f((unsigned short)h0[jj]), w0, a[jj]);
        }
        #pragma unroll
        for (int jj = 0; jj < 8; ++jj) {
            a[jj] += __shfl_xor(a[jj], 16);
            a[jj] += __shfl_xor(a[jj], 32);
        }
        if (q == 0) {
            bf16x8 ov;
            #pragma unroll
            for (int jj = 0; jj < 8; ++jj)
                ov[jj] = (short)f2b(fmaxf(a[jj] + bias[l4 * 8 + jj], 0.f));
            *(bf16x8*)&xt[wave][r][l4 * 8] = ov;
        }
    }

    // ---- MFMA: 16x128 X-tile @ 128x128 W -> 16x128 Hout tile ----
    // A-frag: row = lane&15, k-group = lane>>4, 8 consecutive k per frag step
    bf16x8 afrag[4];
    #pragma unroll
    for (int ks = 0; ks < 4; ++ks)
        afrag[ks] = *(const bf16x8*)&xt[wave][l4][q * 8 + ks * 32];

    #pragma unroll
    for (int nt = 0; nt < 8; ++nt) {
        f32x4 acc = {0.f, 0.f, 0.f, 0.f};
        const unsigned short* wp = Wt + (size_t)(nt * 16 + l4) * HD + q * 8;
        #pragma unroll
        for (int ks = 0; ks < 4; ++ks) {
            bf16x8 bfrag = *(const bf16x8*)(wp + ks * 32);
            acc = __builtin_amdgcn_mfma_f32_16x16x32_bf16(afrag[ks], bfrag, acc, 0, 0, 0);
        }
        #pragma unroll
        for (int j = 0; j < 4; ++j) {
            int row = v0 + q * 4 + j;   // C/D: col = lane&15, row = (lane>>4)*4 + reg
            if (row < NV)
                Hout[(size_t)row * HD + nt * 16 + l4] = f2b(acc[j]);
        }
    }
}

// ---------- plain aggregate (last layer): one wave per dst, quarter-waves ----------
__global__ __launch_bounds__(256) void k_agg(const unsigned short* __restrict__ H,
                                             const float* __restrict__ dinv,
                                             const int* __restrict__ rowstart,
                                             const int* __restrict__ degi,
                                             const int* __restrict__ csr_src,
                                             const float* __restrict__ bias,
                                             unsigned short* __restrict__ Xo) {
    int gtid = blockIdx.x * 256 + threadIdx.x;
    int v = gtid >> 6;
    if (v >= NV) return;
    int lane = threadIdx.x & 63;
    int q = lane >> 4;
    int l4 = lane & 15;
    float di = dinv[v];
    int rs = rowstart[v], len = degi[v];
    float a[8];
    if (q == 0) {
        float sc = di * di;
        bf16x8 hv = *(const bf16x8*)(H + (size_t)v * HD + l4 * 8);
        #pragma unroll
        for (int jj = 0; jj < 8; ++jj) a[jj] = b2f((unsigned short)hv[jj]) * sc;
    } else {
        #pragma unroll
        for (int jj = 0; jj < 8; ++jj) a[jj] = 0.f;
    }
    int cnt = (len - q + 3) >> 2;
    int idx = rs + q;
    int j = 0;
    for (; j + 1 < cnt; j += 2) {
        int s0 = csr_src[idx], s1 = csr_src[idx + 4];
        idx += 8;
        float w0 = dinv[s0] * di, w1 = dinv[s1] * di;
        bf16x8 h0 = *(const bf16x8*)(H + (size_t)s0 * HD + l4 * 8);
        bf16x8 h1 = *(const bf16x8*)(H + (size_t)s1 * HD + l4 * 8);
        #pragma unroll
        for (int jj = 0; jj < 8; ++jj) {
            a[jj] = fmaf(b2f((unsigned short)h0[jj]), w0, a[jj]);
            a[jj] = fmaf(b2f((unsigned short)h1[jj]), w1, a[jj]);
        }
    }
    if (j < cnt) {
        int s0 = csr_src[idx];
        float w0 = dinv[s0] * di;
        bf16x8 h0 = *(const bf16x8*)(H + (size_t)s0 * HD + l4 * 8);
        #pragma unroll
        for (int jj = 0; jj < 8; ++jj)
            a[jj] = fmaf(b2f((unsigned short)h0[jj]), w0, a[jj]);
    }
    #pragma unroll
    for (int jj = 0; jj < 8; ++jj) {
        a[jj] += __shfl_xor(a[jj], 16);
        a[jj] += __shfl_xor(a[jj], 32);
    }
    if (q == 0) {
        bf16x8 ov;
        #pragma unroll
        for (int jj = 0; jj < 8; ++jj)
            ov[jj] = (short)f2b(fmaxf(a[jj] + bias[l4 * 8 + jj], 0.f));
        *(bf16x8*)(Xo + (size_t)v * HD + l4 * 8) = ov;
    }
}

// ---------- mean pool: 2048 blocks x 256 thr, register run-length accumulate ----------
__global__ __launch_bounds__(256) void k_pool(const unsigned short* __restrict__ X,
                                              const int* __restrict__ batch,
                                              float* __restrict__ pool,
                                              int* __restrict__ cnt) {
    constexpr int NCHUNK = 2048;
    constexpr int CHUNK = (NV + NCHUNK - 1) / NCHUNK;  // 49
    int c = threadIdx.x & 127;
    int r = threadIdx.x >> 7;
    int v0 = blockIdx.x * CHUNK;
    if (v0 >= NV) return;
    int vend = min(v0 + CHUNK, NV);
    int cur = -1;
    float sum = 0.f;
    for (int v = v0 + r; v < vend; v += 2) {
        int bb = batch[v];
        if (bb != cur) {
            if (cur >= 0) atomicAdd(&pool[cur * HD + c], sum);
            cur = bb; sum = 0.f;
        }
        sum += b2f(X[(size_t)v * HD + c]);
    }
    if (cur >= 0) atomicAdd(&pool[cur * HD + c], sum);
    if (threadIdx.x == 0) {
        int prev = batch[v0]; int c0 = 0;
        for (int v = v0; v < vend; ++v) {
            int bb = batch[v];
            if (bb != prev) { atomicAdd(&cnt[prev], c0); prev = bb; c0 = 0; }
            ++c0;
        }
        atomicAdd(&cnt[prev], c0);
    }
}

// ---------- final linear + layernorm, one block per graph ----------
__global__ __launch_bounds__(256) void k_out(const float* __restrict__ pool,
                                             const int* __restrict__ cnt,
                                             const float* __restrict__ Wout,
                                             const float* __restrict__ bout,
                                             const float* __restrict__ gamma,
                                             const float* __restrict__ beta,
                                             float* __restrict__ out) {
    __shared__ float ps[HD];
    __shared__ float red[DM];
    int g = blockIdx.x, t = threadIdx.x;
    if (t < HD) {
        float cn = fmaxf((float)cnt[g], 1.0f);
        ps[t] = pool[g * HD + t] / cn;
    }
    __syncthreads();
    float acc = bout[t];
    #pragma unroll 8
    for (int k = 0; k < HD; ++k) acc = fmaf(ps[k], Wout[k * DM + t], acc);
    red[t] = acc; __syncthreads();
    for (int s2 = 128; s2 > 0; s2 >>= 1) {
        if (t < s2) red[t] += red[t + s2];
        __syncthreads();
    }
    float mu = red[0] * (1.0f / DM);
    __syncthreads();
    float d = acc - mu;
    red[t] = d * d; __syncthreads();
    for (int s2 = 128; s2 > 0; s2 >>= 1) {
        if (t < s2) red[t] += red[t + s2];
        __syncthreads();
    }
    float var = red[0] * (1.0f / DM);
    out[g * DM + t] = d * rsqrtf(var + EPSLN) * gamma[t] + beta[t];
}

extern "C" void kernel_launch(void* const* d_in, const int* in_sizes, int n_in,
                              void* d_out, int out_size, void* d_ws, size_t ws_size,
                              hipStream_t stream) {
    const float* verts = (const float*)d_in[0];
    const int*   ei    = (const int*)d_in[1];
    const int*   batch = (const int*)d_in[2];
    const float* Win   = (const float*)d_in[3];
    const float* bin   = (const float*)d_in[4];
    const float* W1    = (const float*)d_in[5];
    const float* b1    = (const float*)d_in[6];
    const float* W2    = (const float*)d_in[7];
    const float* b2    = (const float*)d_in[8];
    const float* W3    = (const float*)d_in[9];
    const float* b3    = (const float*)d_in[10];
    const float* Wout  = (const float*)d_in[11];
    const float* bout  = (const float*)d_in[12];
    const float* gamma = (const float*)d_in[13];
    const float* beta  = (const float*)d_in[14];
    float* out = (float*)d_out;

    char* wp = (char*)d_ws;
    auto alloc = [&](size_t bytes) -> char* {
        char* p = wp;
        wp += (bytes + 255) & ~(size_t)255;
        return p;
    };
    unsigned short* bufA = (unsigned short*)alloc((size_t)NV * HD * 2);
    unsigned short* bufB = (unsigned short*)alloc((size_t)NV * HD * 2);
    unsigned short* Wt   = (unsigned short*)alloc((size_t)2 * HD * HD * 2);
    int*   degi     = (int*)alloc((size_t)NV * 4);
    float* dinv     = (float*)alloc((size_t)NV * 4);
    int*   rowstart = (int*)alloc((size_t)NV * 4);
    int*   csr      = (int*)alloc((size_t)NE * 4);
    int*   ebuf     = (int*)alloc((size_t)NE * 4);
    int*   bcount   = (int*)alloc((size_t)NBUCK * 4);
    int*   bstart   = (int*)alloc((size_t)(NBUCK + 1) * 4);
    int*   bcursor  = (int*)alloc((size_t)NBUCK * 4);
    float* pool     = (float*)alloc((size_t)NB * HD * 4);
    int*   cnt      = (int*)alloc((size_t)NB * 4);

    hipMemsetAsync(bcount, 0, (size_t)NBUCK * 4, stream);
    hipMemsetAsync(pool,   0, (size_t)NB * HD * 4, stream);
    hipMemsetAsync(cnt,    0, (size_t)NB * 4, stream);

    // CSR build (bucketed, L2-local)
    k_bhist<<<NEB, 256, 0, stream>>>(ei, bcount);
    k_bscan<<<1, 64, 0, stream>>>(bcount, bstart, bcursor);
    k_bscatter<<<NEB, 256, 0, stream>>>(ei, bcursor, ebuf);
    k_bcsr<<<NBUCK, 256, 0, stream>>>(ebuf, bstart, degi, dinv, rowstart, csr);

    // weights prep + layer-1 H (input linear folded)
    k_wt2<<<(2 * HD * HD + 255) / 256, 256, 0, stream>>>(W2, W3, Wt);
    k_h1<<<1024, 256, 0, stream>>>(verts, Win, bin, W1, bufA);

    // layer 1: agg+relu+GEMM(W2) fused ; layer 2: agg+relu+GEMM(W3) fused
    k_aggf<<<(NV + 63) / 64, 256, 0, stream>>>(bufA, dinv, rowstart, degi, csr, b1, Wt, bufB);
    k_aggf<<<(NV + 63) / 64, 256, 0, stream>>>(bufB, dinv, rowstart, degi, csr, b2, Wt + (size_t)HD * HD, bufA);
    // layer 3: plain agg
    k_agg<<<((size_t)NV * 64 + 255) / 256, 256, 0, stream>>>(bufA, dinv, rowstart, degi, csr, b3, bufB);

    k_pool<<<2048, 256, 0, stream>>>(bufB, batch, pool, cnt);
    k_out<<<NB, 256, 0, stream>>>(pool, cnt, Wout, bout, gamma, beta, out);
}

// Round 9
// 369.538 us; speedup vs baseline: 1.0995x; 1.0019x over previous
//
#include <hip/hip_runtime.h>

// Problem constants (match reference setup_inputs)
constexpr int NV = 100000;   // vertices
constexpr int NE = 1600000;  // directed edges
constexpr int NB = 64;       // graphs
constexpr int HD = 128;      // hidden
constexpr int DM = 256;      // out dim
#define EPSLN 1e-5f

// CSR bucketing
constexpr int DPB   = 512;                      // dsts per bucket
constexpr int NBUCK = (NV + DPB - 1) / DPB;     // 196
constexpr int EPB   = 4096;                     // edges per block (bucket kernels)
constexpr int NEB   = (NE + EPB - 1) / EPB;     // 391

typedef short bf16x8 __attribute__((ext_vector_type(8)));
typedef float f32x4 __attribute__((ext_vector_type(4)));

__device__ inline unsigned short f2b(float f) {
    union { float f; unsigned u; } x; x.f = f;
    unsigned r = x.u + 0x7FFF + ((x.u >> 16) & 1);
    return (unsigned short)(r >> 16);
}
__device__ inline float b2f(unsigned short h) {
    union { unsigned u; float f; } x; x.u = (unsigned)h << 16;
    return x.f;
}

// ---------- bucket histogram: count edges per dst-bucket ----------
__global__ __launch_bounds__(256) void k_bhist(const int* __restrict__ ei,
                                               int* __restrict__ bcount) {
    __shared__ int h[NBUCK];
    int t = threadIdx.x;
    for (int i = t; i < NBUCK; i += 256) h[i] = 0;
    __syncthreads();
    int base = blockIdx.x * EPB;
    #pragma unroll
    for (int j = 0; j < EPB / 256; ++j) {
        int idx = base + j * 256 + t;
        if (idx < NE) atomicAdd(&h[ei[NE + idx] >> 9], 1);
    }
    __syncthreads();
    for (int i = t; i < NBUCK; i += 256) if (h[i]) atomicAdd(&bcount[i], h[i]);
}

__global__ void k_bscan(const int* __restrict__ bcount, int* __restrict__ bstart,
                        int* __restrict__ bcursor) {
    if (threadIdx.x == 0 && blockIdx.x == 0) {
        int run = 0;
        for (int i = 0; i < NBUCK; ++i) { bstart[i] = run; bcursor[i] = run; run += bcount[i]; }
        bstart[NBUCK] = run;
    }
}

// ---------- scatter edges into bucket regions (packed: (src<<9)|dstloc) ----------
__global__ __launch_bounds__(256) void k_bscatter(const int* __restrict__ ei,
                                                  int* __restrict__ bcursor,
                                                  int* __restrict__ ebuf) {
    __shared__ int h[NBUCK];
    __shared__ int lbase[NBUCK];
    int t = threadIdx.x;
    for (int i = t; i < NBUCK; i += 256) h[i] = 0;
    __syncthreads();
    int base = blockIdx.x * EPB;
    int s[16], d[16], rk[16];
    #pragma unroll
    for (int j = 0; j < 16; ++j) {
        int idx = base + j * 256 + t;
        if (idx < NE) {
            s[j] = ei[idx];
            d[j] = ei[NE + idx];
            rk[j] = atomicAdd(&h[d[j] >> 9], 1);
        } else d[j] = -1;
    }
    __syncthreads();
    for (int i = t; i < NBUCK; i += 256) {
        int c = h[i];
        if (c) lbase[i] = atomicAdd(&bcursor[i], c);
    }
    __syncthreads();
    #pragma unroll
    for (int j = 0; j < 16; ++j)
        if (d[j] >= 0) ebuf[lbase[d[j] >> 9] + rk[j]] = (s[j] << 9) | (d[j] & 511);
}

// ---------- fused per-bucket: histogram -> local scan -> deg/dinv/rowstart -> CSR fill ----------
__global__ __launch_bounds__(256) void k_bcsr(const int* __restrict__ ebuf,
                                              const int* __restrict__ bstart,
                                              int* __restrict__ degi,
                                              float* __restrict__ dinv,
                                              int* __restrict__ rowstart,
                                              int* __restrict__ csr) {
    __shared__ int h[DPB];
    __shared__ int sdata[256];
    int b = blockIdx.x, t = threadIdx.x, d0 = b * DPB;
    for (int i = t; i < DPB; i += 256) h[i] = 0;
    __syncthreads();
    int e0 = bstart[b], e1 = bstart[b + 1];
    for (int e = e0 + t; e < e1; e += 256) atomicAdd(&h[ebuf[e] & 511], 1);
    __syncthreads();
    int a = h[2 * t], c = h[2 * t + 1];
    sdata[t] = a + c;
    __syncthreads();
    for (int off = 1; off < 256; off <<= 1) {
        int v = sdata[t];
        int add = (t >= off) ? sdata[t - off] : 0;
        __syncthreads();
        sdata[t] = v + add;
        __syncthreads();
    }
    int excl = (t == 0) ? 0 : sdata[t - 1];
    int base = bstart[b];
    int v0 = d0 + 2 * t, v1 = v0 + 1;
    if (v0 < NV) { rowstart[v0] = base + excl;     degi[v0] = a; dinv[v0] = rsqrtf((float)a + 1.0f); }
    if (v1 < NV) { rowstart[v1] = base + excl + a; degi[v1] = c; dinv[v1] = rsqrtf((float)c + 1.0f); }
    // reuse h as cursors
    h[2 * t]     = base + excl;
    h[2 * t + 1] = base + excl + a;
    __syncthreads();
    for (int e = e0 + t; e < e1; e += 256) {
        int p = ebuf[e];
        int slot = atomicAdd(&h[p & 511], 1);
        csr[slot] = p >> 9;
    }
}

// ---------- layer-1 H from vertices; folds Wc = Win@W1, bc = bin@W1 per block ----------
__global__ __launch_bounds__(256) void k_h1(const float* __restrict__ verts,
                                            const float* __restrict__ Win,
                                            const float* __restrict__ bin,
                                            const float* __restrict__ W1,
                                            unsigned short* __restrict__ Hb) {
    __shared__ float Wc[3 * HD];
    __shared__ float bc[HD];
    int t = threadIdx.x;
    if (t < HD) {
        float w0 = 0.f, w1 = 0.f, w2 = 0.f, bv = 0.f;
        for (int k = 0; k < HD; ++k) {
            float w = W1[k * HD + t];
            w0 = fmaf(Win[k], w, w0);
            w1 = fmaf(Win[128 + k], w, w1);
            w2 = fmaf(Win[256 + k], w, w2);
            bv = fmaf(bin[k], w, bv);
        }
        Wc[t] = w0; Wc[128 + t] = w1; Wc[256 + t] = w2; bc[t] = bv;
    }
    __syncthreads();
    for (int idx = blockIdx.x * 256 + t; idx < NV * HD; idx += gridDim.x * 256) {
        int v = idx >> 7, c = idx & 127;
        float a = verts[v * 3 + 0], b = verts[v * 3 + 1], d = verts[v * 3 + 2];
        Hb[idx] = f2b(bc[c] + a * Wc[c] + b * Wc[128 + c] + d * Wc[256 + c]);
    }
}

// ---------- W2,W3 [k][n] f32 -> Wt [l][n][k] bf16 ----------
__global__ void k_wt2(const float* __restrict__ W2, const float* __restrict__ W3,
                      unsigned short* __restrict__ Wt) {
    int idx = blockIdx.x * 256 + threadIdx.x;
    if (idx >= 2 * HD * HD) return;
    int l = idx >> 14, r = idx & 16383;
    const float* W = (l == 0) ? W2 : W3;
    int n = r >> 7, k = r & 127;
    Wt[idx - r + n * HD + k] = f2b(W[k * HD + n]);
}

// ---------- FUSED aggregate+relu+GEMM: block (4 waves) owns a 16-row tile ----------
// each wave aggregates 4 rows -> LDS; barrier; waves split GEMM by col-chunks
__global__ __launch_bounds__(256) void k_aggf(const unsigned short* __restrict__ H,
                                              const float* __restrict__ dinv,
                                              const int* __restrict__ rowstart,
                                              const int* __restrict__ degi,
                                              const int* __restrict__ csr_src,
                                              const float* __restrict__ bias,
                                              const unsigned short* __restrict__ Wt,
                                              unsigned short* __restrict__ Hout) {
    __shared__ __align__(16) unsigned short xt[16][136];  // padded stride
    int wave = threadIdx.x >> 6;
    int lane = threadIdx.x & 63;
    int q = lane >> 4;        // quarter 0..3: edges q, q+4, ...
    int l4 = lane & 15;       // col group: cols l4*8 .. l4*8+7
    int v0 = blockIdx.x * 16;  // NV % 16 == 0

    // ---- each wave aggregates 4 rows into LDS (relu'd bf16) ----
    #pragma unroll
    for (int i = 0; i < 4; ++i) {
        int r = wave * 4 + i;
        int v = v0 + r;
        float di = dinv[v];
        int rs = rowstart[v], len = degi[v];
        float a[8];
        if (q == 0) {
            float sc = di * di;
            bf16x8 hv = *(const bf16x8*)(H + (size_t)v * HD + l4 * 8);
            #pragma unroll
            for (int jj = 0; jj < 8; ++jj) a[jj] = b2f((unsigned short)hv[jj]) * sc;
        } else {
            #pragma unroll
            for (int jj = 0; jj < 8; ++jj) a[jj] = 0.f;
        }
        int cnt = (len - q + 3) >> 2;
        int idx = rs + q;
        int j = 0;
        for (; j + 1 < cnt; j += 2) {
            int s0 = csr_src[idx], s1 = csr_src[idx + 4];
            idx += 8;
            float w0 = dinv[s0] * di, w1 = dinv[s1] * di;
            bf16x8 h0 = *(const bf16x8*)(H + (size_t)s0 * HD + l4 * 8);
            bf16x8 h1 = *(const bf16x8*)(H + (size_t)s1 * HD + l4 * 8);
            #pragma unroll
            for (int jj = 0; jj < 8; ++jj) {
                a[jj] = fmaf(b2f((unsigned short)h0[jj]), w0, a[jj]);
                a[jj] = fmaf(b2f((unsigned short)h1[jj]), w1, a[jj]);
            }
        }
        if (j < cnt) {
            int s0 = csr_src[idx];
            float w0 = dinv[s0] * di;
            bf16x8 h0 = *(const bf16x8*)(H + (size_t)s0 * HD + l4 * 8);
            #pragma unroll
            for (int jj = 0; jj < 8; ++jj)
                a[jj] = fmaf(b2f((unsigned short)h0[jj]), w0, a[jj]);
        }
        #pragma unroll
        for (int jj = 0; jj < 8; ++jj) {
            a[jj] += __shfl_xor(a[jj], 16);
            a[jj] += __shfl_xor(a[jj], 32);
        }
        if (q == 0) {
            bf16x8 ov;
            #pragma unroll
            for (int jj = 0; jj < 8; ++jj)
                ov[jj] = (short)f2b(fmaxf(a[jj] + bias[l4 * 8 + jj], 0.f));
            *(bf16x8*)&xt[r][l4 * 8] = ov;
        }
    }
    __syncthreads();

    // ---- MFMA: 16x128 X-tile @ 128x128 W; wave computes col-chunks nt=2w,2w+1 ----
    bf16x8 afrag[4];
    #pragma unroll
    for (int ks = 0; ks < 4; ++ks)
        afrag[ks] = *(const bf16x8*)&xt[l4][q * 8 + ks * 32];

    #pragma unroll
    for (int nn = 0; nn < 2; ++nn) {
        int nt = wave * 2 + nn;
        f32x4 acc = {0.f, 0.f, 0.f, 0.f};
        const unsigned short* wp = Wt + (size_t)(nt * 16 + l4) * HD + q * 8;
        #pragma unroll
        for (int ks = 0; ks < 4; ++ks) {
            bf16x8 bfrag = *(const bf16x8*)(wp + ks * 32);
            acc = __builtin_amdgcn_mfma_f32_16x16x32_bf16(afrag[ks], bfrag, acc, 0, 0, 0);
        }
        #pragma unroll
        for (int j = 0; j < 4; ++j) {
            int row = v0 + q * 4 + j;   // C/D: col = lane&15, row = (lane>>4)*4 + reg
            Hout[(size_t)row * HD + nt * 16 + l4] = f2b(acc[j]);
        }
    }
}

// ---------- plain aggregate (last layer): one wave per dst, quarter-waves ----------
__global__ __launch_bounds__(256) void k_agg(const unsigned short* __restrict__ H,
                                             const float* __restrict__ dinv,
                                             const int* __restrict__ rowstart,
                                             const int* __restrict__ degi,
                                             const int* __restrict__ csr_src,
                                             const float* __restrict__ bias,
                                             unsigned short* __restrict__ Xo) {
    int gtid = blockIdx.x * 256 + threadIdx.x;
    int v = gtid >> 6;
    if (v >= NV) return;
    int lane = threadIdx.x & 63;
    int q = lane >> 4;
    int l4 = lane & 15;
    float di = dinv[v];
    int rs = rowstart[v], len = degi[v];
    float a[8];
    if (q == 0) {
        float sc = di * di;
        bf16x8 hv = *(const bf16x8*)(H + (size_t)v * HD + l4 * 8);
        #pragma unroll
        for (int jj = 0; jj < 8; ++jj) a[jj] = b2f((unsigned short)hv[jj]) * sc;
    } else {
        #pragma unroll
        for (int jj = 0; jj < 8; ++jj) a[jj] = 0.f;
    }
    int cnt = (len - q + 3) >> 2;
    int idx = rs + q;
    int j = 0;
    for (; j + 1 < cnt; j += 2) {
        int s0 = csr_src[idx], s1 = csr_src[idx + 4];
        idx += 8;
        float w0 = dinv[s0] * di, w1 = dinv[s1] * di;
        bf16x8 h0 = *(const bf16x8*)(H + (size_t)s0 * HD + l4 * 8);
        bf16x8 h1 = *(const bf16x8*)(H + (size_t)s1 * HD + l4 * 8);
        #pragma unroll
        for (int jj = 0; jj < 8; ++jj) {
            a[jj] = fmaf(b2f((unsigned short)h0[jj]), w0, a[jj]);
            a[jj] = fmaf(b2f((unsigned short)h1[jj]), w1, a[jj]);
        }
    }
    if (j < cnt) {
        int s0 = csr_src[idx];
        float w0 = dinv[s0] * di;
        bf16x8 h0 = *(const bf16x8*)(H + (size_t)s0 * HD + l4 * 8);
        #pragma unroll
        for (int jj = 0; jj < 8; ++jj)
            a[jj] = fmaf(b2f((unsigned short)h0[jj]), w0, a[jj]);
    }
    #pragma unroll
    for (int jj = 0; jj < 8; ++jj) {
        a[jj] += __shfl_xor(a[jj], 16);
        a[jj] += __shfl_xor(a[jj], 32);
    }
    if (q == 0) {
        bf16x8 ov;
        #pragma unroll
        for (int jj = 0; jj < 8; ++jj)
            ov[jj] = (short)f2b(fmaxf(a[jj] + bias[l4 * 8 + jj], 0.f));
        *(bf16x8*)(Xo + (size_t)v * HD + l4 * 8) = ov;
    }
}

// ---------- mean pool: 2048 blocks x 256 thr, register run-length accumulate ----------
__global__ __launch_bounds__(256) void k_pool(const unsigned short* __restrict__ X,
                                              const int* __restrict__ batch,
                                              float* __restrict__ pool,
                                              int* __restrict__ cnt) {
    constexpr int NCHUNK = 2048;
    constexpr int CHUNK = (NV + NCHUNK - 1) / NCHUNK;  // 49
    int c = threadIdx.x & 127;
    int r = threadIdx.x >> 7;
    int v0 = blockIdx.x * CHUNK;
    if (v0 >= NV) return;
    int vend = min(v0 + CHUNK, NV);
    int cur = -1;
    float sum = 0.f;
    for (int v = v0 + r; v < vend; v += 2) {
        int bb = batch[v];
        if (bb != cur) {
            if (cur >= 0) atomicAdd(&pool[cur * HD + c], sum);
            cur = bb; sum = 0.f;
        }
        sum += b2f(X[(size_t)v * HD + c]);
    }
    if (cur >= 0) atomicAdd(&pool[cur * HD + c], sum);
    if (threadIdx.x == 0) {
        int prev = batch[v0]; int c0 = 0;
        for (int v = v0; v < vend; ++v) {
            int bb = batch[v];
            if (bb != prev) { atomicAdd(&cnt[prev], c0); prev = bb; c0 = 0; }
            ++c0;
        }
        atomicAdd(&cnt[prev], c0);
    }
}

// ---------- final linear + layernorm, one block per graph ----------
__global__ __launch_bounds__(256) void k_out(const float* __restrict__ pool,
                                             const int* __restrict__ cnt,
                                             const float* __restrict__ Wout,
                                             const float* __restrict__ bout,
                                             const float* __restrict__ gamma,
                                             const float* __restrict__ beta,
                                             float* __restrict__ out) {
    __shared__ float ps[HD];
    __shared__ float red[DM];
    int g = blockIdx.x, t = threadIdx.x;
    if (t < HD) {
        float cn = fmaxf((float)cnt[g], 1.0f);
        ps[t] = pool[g * HD + t] / cn;
    }
    __syncthreads();
    float acc = bout[t];
    #pragma unroll 8
    for (int k = 0; k < HD; ++k) acc = fmaf(ps[k], Wout[k * DM + t], acc);
    red[t] = acc; __syncthreads();
    for (int s2 = 128; s2 > 0; s2 >>= 1) {
        if (t < s2) red[t] += red[t + s2];
        __syncthreads();
    }
    float mu = red[0] * (1.0f / DM);
    __syncthreads();
    float d = acc - mu;
    red[t] = d * d; __syncthreads();
    for (int s2 = 128; s2 > 0; s2 >>= 1) {
        if (t < s2) red[t] += red[t + s2];
        __syncthreads();
    }
    float var = red[0] * (1.0f / DM);
    out[g * DM + t] = d * rsqrtf(var + EPSLN) * gamma[t] + beta[t];
}

extern "C" void kernel_launch(void* const* d_in, const int* in_sizes, int n_in,
                              void* d_out, int out_size, void* d_ws, size_t ws_size,
                              hipStream_t stream) {
    const float* verts = (const float*)d_in[0];
    const int*   ei    = (const int*)d_in[1];
    const int*   batch = (const int*)d_in[2];
    const float* Win   = (const float*)d_in[3];
    const float* bin   = (const float*)d_in[4];
    const float* W1    = (const float*)d_in[5];
    const float* b1    = (const float*)d_in[6];
    const float* W2    = (const float*)d_in[7];
    const float* b2    = (const float*)d_in[8];
    const float* W3    = (const float*)d_in[9];
    const float* b3    = (const float*)d_in[10];
    const float* Wout  = (const float*)d_in[11];
    const float* bout  = (const float*)d_in[12];
    const float* gamma = (const float*)d_in[13];
    const float* beta  = (const float*)d_in[14];
    float* out = (float*)d_out;

    char* wp = (char*)d_ws;
    auto alloc = [&](size_t bytes) -> char* {
        char* p = wp;
        wp += (bytes + 255) & ~(size_t)255;
        return p;
    };
    unsigned short* bufA = (unsigned short*)alloc((size_t)NV * HD * 2);
    unsigned short* bufB = (unsigned short*)alloc((size_t)NV * HD * 2);
    unsigned short* Wt   = (unsigned short*)alloc((size_t)2 * HD * HD * 2);
    int*   degi     = (int*)alloc((size_t)NV * 4);
    float* dinv     = (float*)alloc((size_t)NV * 4);
    int*   rowstart = (int*)alloc((size_t)NV * 4);
    int*   csr      = (int*)alloc((size_t)NE * 4);
    int*   ebuf     = (int*)alloc((size_t)NE * 4);
    int*   bcount   = (int*)alloc((size_t)NBUCK * 4);
    int*   bstart   = (int*)alloc((size_t)(NBUCK + 1) * 4);
    int*   bcursor  = (int*)alloc((size_t)NBUCK * 4);
    float* pool     = (float*)alloc((size_t)NB * HD * 4);
    int*   cnt      = (int*)alloc((size_t)NB * 4);

    hipMemsetAsync(bcount, 0, (size_t)NBUCK * 4, stream);
    hipMemsetAsync(pool,   0, (size_t)NB * HD * 4, stream);
    hipMemsetAsync(cnt,    0, (size_t)NB * 4, stream);

    // CSR build (bucketed, L2-local)
    k_bhist<<<NEB, 256, 0, stream>>>(ei, bcount);
    k_bscan<<<1, 64, 0, stream>>>(bcount, bstart, bcursor);
    k_bscatter<<<NEB, 256, 0, stream>>>(ei, bcursor, ebuf);
    k_bcsr<<<NBUCK, 256, 0, stream>>>(ebuf, bstart, degi, dinv, rowstart, csr);

    // weights prep + layer-1 H (input linear folded)
    k_wt2<<<(2 * HD * HD + 255) / 256, 256, 0, stream>>>(W2, W3, Wt);
    k_h1<<<1024, 256, 0, stream>>>(verts, Win, bin, W1, bufA);

    // layer 1: agg+relu+GEMM(W2) fused ; layer 2: agg+relu+GEMM(W3) fused
    k_aggf<<<NV / 16, 256, 0, stream>>>(bufA, dinv, rowstart, degi, csr, b1, Wt, bufB);
    k_aggf<<<NV / 16, 256, 0, stream>>>(bufB, dinv, rowstart, degi, csr, b2, Wt + (size_t)HD * HD, bufA);
    // layer 3: plain agg
    k_agg<<<((size_t)NV * 64 + 255) / 256, 256, 0, stream>>>(bufA, dinv, rowstart, degi, csr, b3, bufB);

    k_pool<<<2048, 256, 0, stream>>>(bufB, batch, pool, cnt);
    k_out<<<NB, 256, 0, stream>>>(pool, cnt, Wout, bout, gamma, beta, out);
}